// Round 6
// baseline (203.008 us; speedup 1.0000x reference)
//
#include <hip/hip_runtime.h>
#include <math.h>

constexpr int B = 4;
constexpr int N = 8192;
constexpr int KNN = 8;
constexpr int SLICES = 8;      // candidate slices == waves per block
constexpr int Q = 2;           // queries per lane
constexpr int QPB = 64 * Q;    // queries per block = 128
constexpr int L = N / SLICES;  // 1024 candidates per slice
constexpr int CHUNK = 64;      // candidates staged per LDS chunk
constexpr int NCHUNK = L / CHUNK;

// Prologue: pack pred = src+flow and target as float4 (x, y, z, |p|^2/2).
// Also zeroes the output accumulator (harness poisons it before each call).
__global__ __launch_bounds__(256) void prep_kernel(
    const float* __restrict__ src, const float* __restrict__ tgt,
    const float* __restrict__ flow, float4* __restrict__ pred4,
    float4* __restrict__ tgt4, float* __restrict__ out) {
  int i = blockIdx.x * 256 + threadIdx.x;
  if (i == 0) out[0] = 0.0f;
  if (i >= B * N) return;
  float px = src[3 * i + 0] + flow[3 * i + 0];
  float py = src[3 * i + 1] + flow[3 * i + 1];
  float pz = src[3 * i + 2] + flow[3 * i + 2];
  pred4[i] = make_float4(px, py, pz, 0.5f * (px * px + py * py + pz * pz));
  float tx = tgt[3 * i + 0];
  float ty = tgt[3 * i + 1];
  float tz = tgt[3 * i + 2];
  tgt4[i] = make_float4(tx, ty, tz, 0.5f * (tx * tx + ty * ty + tz * tz));
}

// Insert tv into sorted ascending d[0..7], keeping the smallest 8 sorted.
// Exact identity: d'[0] = min(d0,tv); d'[i] = med3(d[i-1], d[i], tv).
// 8 independent ops (depth 1).
__device__ __forceinline__ void insert8(float (&d)[KNN], float tv) {
  float n0 = fminf(d[0], tv);
  float n1 = __builtin_amdgcn_fmed3f(d[0], d[1], tv);
  float n2 = __builtin_amdgcn_fmed3f(d[1], d[2], tv);
  float n3 = __builtin_amdgcn_fmed3f(d[2], d[3], tv);
  float n4 = __builtin_amdgcn_fmed3f(d[3], d[4], tv);
  float n5 = __builtin_amdgcn_fmed3f(d[4], d[5], tv);
  float n6 = __builtin_amdgcn_fmed3f(d[5], d[6], tv);
  float n7 = __builtin_amdgcn_fmed3f(d[6], d[7], tv);
  d[0] = n0; d[1] = n1; d[2] = n2; d[3] = n3;
  d[4] = n4; d[5] = n5; d[6] = n6; d[7] = n7;
}

// Block = 8 waves of 64 lanes; wave w scans candidate slice w for 128
// queries (TWO per lane) — each broadcast ds_read_b128 now feeds 2 insert
// chains, halving CU-level LDS issue (the round-5 bottleneck: 12 cy/b128
// x 32 wave-kcand = 393 K cy/CU vs 196 K VALU). Candidates staged per-wave
// into double-buffered LDS via coalesced global_load_dwordx4 + ds_write.
__global__ __launch_bounds__(512, 4) void chamfer_kernel(
    const float4* __restrict__ pred4, const float4* __restrict__ tgt4,
    float* __restrict__ out) {
  int blk = blockIdx.x;           // 512 blocks
  int dir = blk >> 8;             // 0: pred->tgt, 1: tgt->pred
  int batch = (blk >> 6) & 3;     // 4 batches
  int chunk = blk & 63;           // 64 chunks of 128 queries
  const float4* __restrict__ qarr = (dir == 0 ? pred4 : tgt4) + batch * N;
  const float4* __restrict__ parr = (dir == 0 ? tgt4 : pred4) + batch * N;

  int lane = threadIdx.x & 63;
  int wave = threadIdx.x >> 6;

  float4 qa = qarr[chunk * QPB + lane];
  float4 qb = qarr[chunk * QPB + 64 + lane];
  float nqax = -qa.x, nqay = -qa.y, nqaz = -qa.z;
  float nqbx = -qb.x, nqby = -qb.y, nqbz = -qb.z;
  const float4* __restrict__ p0 = parr + wave * L;

  __shared__ float4 stage[SLICES][2][CHUNK];   // 16 KB, per-wave dbuf
  __shared__ float part[SLICES][QPB][KNN + 1]; // 36 KB, slice merge

  float da[KNN], db[KNN];
#pragma unroll
  for (int i = 0; i < KNN; ++i) { da[i] = INFINITY; db[i] = INFINITY; }

  float4 my = p0[lane];  // prefetch chunk 0 (coalesced, 1 KB per wave)

  for (int c = 0; c < NCHUNK; ++c) {
    int cur = c & 1;
    stage[wave][cur][lane] = my;               // ds_write_b128
    if (c + 1 < NCHUNK) my = p0[(c + 1) * CHUNK + lane];  // global prefetch
#pragma unroll 8
    for (int i = 0; i < CHUNK; ++i) {
      float4 p = stage[wave][cur][i];          // broadcast ds_read_b128
      float tva = __builtin_fmaf(nqax, p.x,
                  __builtin_fmaf(nqay, p.y,
                  __builtin_fmaf(nqaz, p.z, p.w)));
      float tvb = __builtin_fmaf(nqbx, p.x,
                  __builtin_fmaf(nqby, p.y,
                  __builtin_fmaf(nqbz, p.z, p.w)));
      insert8(da, tva);
      insert8(db, tvb);
    }
  }

  // merge 8 slices' sorted top-8 per query through LDS (stride 9)
#pragma unroll
  for (int i = 0; i < KNN; ++i) {
    part[wave][lane][i] = da[i];
    part[wave][64 + lane][i] = db[i];
  }
  __syncthreads();

  if (wave < 2) {  // wave h merges query group h (its own qa/qb regs apply)
    float m[KNN];
#pragma unroll
    for (int i = 0; i < KNN; ++i) m[i] = part[0][wave * 64 + lane][i];
    for (int s = 1; s < SLICES; ++s) {
#pragma unroll
      for (int i = 0; i < KNN; ++i) insert8(m, part[s][wave * 64 + lane][i]);
    }
    float q2 = 2.0f * (wave == 0 ? qa.w : qb.w);
    float s_ = 0.0f;
#pragma unroll
    for (int i = 0; i < KNN; ++i) {
      float d2 = fmaxf(__builtin_fmaf(2.0f, m[i], q2), 0.0f);
      s_ += sqrtf(d2);
    }
    float val = s_ * (1.0f / KNN);
    for (int off = 32; off; off >>= 1) val += __shfl_down(val, off, 64);
    if (lane == 0) atomicAdd(out, val * (1.0f / (B * N)));
  }
}

extern "C" void kernel_launch(void* const* d_in, const int* in_sizes, int n_in,
                              void* d_out, int out_size, void* d_ws, size_t ws_size,
                              hipStream_t stream) {
  const float* src = (const float*)d_in[0];
  const float* tgt = (const float*)d_in[1];
  const float* flow = (const float*)d_in[2];
  float* out = (float*)d_out;
  float4* pred4 = (float4*)d_ws;
  float4* tgt4 = pred4 + B * N;

  prep_kernel<<<(B * N) / 256, 256, 0, stream>>>(src, tgt, flow, pred4, tgt4, out);
  chamfer_kernel<<<2 * B * (N / QPB), 512, 0, stream>>>(pred4, tgt4, out);
}